// Round 9
// baseline (171.914 us; speedup 1.0000x reference)
//
#include <hip/hip_runtime.h>
#include <math.h>

// EnergyCoulomb: B=32, N=512, D=1024, H=512
// R19: 256x256 GEMM, BK=64. Inline-asm ds_read K-loop (compiler waitcnt
//      pass bypassed). Theory: R12/R16/R18 all plateau at ~6300cy/tile
//      (816 TF = the m97-class 2-barrier ceiling) because the compiler
//      inserts a conservative vmcnt drain before compiler-visible ds_reads
//      that may alias outstanding global_load_lds (R18 = R12 + B-latency
//      confirms the drain survives source-level restructuring). Fix:
//      A-fragment reads are inline-asm ds_read_b128 (opaque to the
//      waitcnt pass -> no alias drain); manual counted s_waitcnt only:
//        per tile: lgkmcnt(0)+sched_barrier after each 8-read half
//        (rule #18), vmcnt(8) at tile end = certifies A(t+1) (issued
//        ~3000cy earlier this tile) while leaving B(t+1)'s 8 loads in
//        flight. Never drains to 0 in the loop.
//      A: 2-buffer LDS (64KB), stage A(t+1) during t (verified swizzle).
//      B: packed fragment-linear regs (R16-verified), prefetch 1 tile
//      ahead, compiler-counted auto-waits (1 tile old -> no stall).
//      Unroll x2: named bufs/B-sets, literal indices (rule #20).
//      prep/coulomb/fallback unchanged from R16.

typedef unsigned short u16;
typedef unsigned int u32;
typedef __bf16 bf16x8 __attribute__((ext_vector_type(8)));
typedef float f32x4 __attribute__((ext_vector_type(4)));

#define GK 1024
#define NT 16

#define GLOAD_LDS16(g, l) __builtin_amdgcn_global_load_lds( \
    (const __attribute__((address_space(1))) void*)(g),     \
    (__attribute__((address_space(3))) void*)(l), 16, 0, 0)

__device__ __forceinline__ u16 f2bf(float f) {
    u32 u = __float_as_uint(f);
    return (u16)((u + 0x7FFFu + ((u >> 16) & 1u)) >> 16);
}

__device__ __forceinline__ float ssp_f(float x) {
    return __logf(0.5f * (__expf(x) + 1.0f));
}

__device__ __forceinline__ float ssp_slow(float x) {
    return fmaxf(x, 0.0f) + log1pf(expf(-fabsf(x))) - 0.6931471805599453f;
}

// ---------------- prep: conv_a + packed conv_w + out zero ------------

__global__ __launch_bounds__(256) void prep(
    const float* __restrict__ rep, const float* __restrict__ W1,
    const float* __restrict__ Wc1, u16* __restrict__ Abf,
    u16* __restrict__ Bp, float* __restrict__ out)
{
    __shared__ float tile[32][33];
    const int blk = blockIdx.x;
    const int t = threadIdx.x;
    if (blk < 8192) {
        int i = (blk * 256 + t) * 8;
        float4 x = *(const float4*)(rep + i);
        float4 y = *(const float4*)(rep + i + 4);
        union { u16 h[8]; uint4 v; } o;
        o.h[0] = f2bf(x.x); o.h[1] = f2bf(x.y); o.h[2] = f2bf(x.z); o.h[3] = f2bf(x.w);
        o.h[4] = f2bf(y.x); o.h[5] = f2bf(y.y); o.h[6] = f2bf(y.z); o.h[7] = f2bf(y.w);
        *(uint4*)(Abf + i) = o.v;
        if (blk == 0 && t < 32) out[t] = 0.0f;
    } else {
        const int bb = blk - 8192;                  // 0..1023
        const int k0 = (bb & 31) * 32;
        const int n0 = (bb >> 5) * 32;              // 0..1023
        const float* src = (n0 < 512) ? W1 : Wc1;
        const int ns0 = (n0 < 512) ? n0 : n0 - 512;
#pragma unroll
        for (int j = 0; j < 4; j++) {
            int idx = j * 256 + t;
            int kl = idx >> 5, nl = idx & 31;
            tile[kl][nl] = src[(size_t)(k0 + kl) * 512 + ns0 + nl];
        }
        __syncthreads();
        // packed fragment-linear write:
        // (n,k) -> Bp[(((n>>4)*32 + (k>>5))*64 + ((k&31)>>3)*16 + (n&15))*8 + (k&7)]
#pragma unroll
        for (int j = 0; j < 4; j++) {
            int idx = j * 256 + t;
            int nl = idx >> 5, kl = idx & 31;
            int n = n0 + nl;
            int c16 = n >> 4, lmv = n & 15;
            int kt32 = k0 >> 5, qv = kl >> 3, jv = kl & 7;
            Bp[(size_t)(((c16 * 32 + kt32) * 64) + qv * 16 + lmv) * 8 + jv] =
                f2bf(tile[kl][nl]);
        }
    }
}

// ---- bf16 MFMA GEMM: 256x256, BK=64, asm-ds_read counted pipeline ----

__global__ __launch_bounds__(512, 2) void gemm_mfma(
    const u16* __restrict__ A,    // [16384][1024] bf16
    const u16* __restrict__ Bp,   // packed fragment-linear, 2 MB
    const float* __restrict__ b1, const float* __restrict__ W2,
    const float* __restrict__ bc1, const float* __restrict__ Wc2,
    float* __restrict__ parts)    // [4][16384]
{
    __shared__ u16 smem[2][16384];                  // 64 KiB: A double-buffer

    // XCD swizzle (256 blocks, 8 XCDs): co-locate the 4 same-bm blocks
    const int blk = blockIdx.x;                     // 0..255
    const int swz = ((blk & 7) << 5) | (blk >> 3);
    const int bm = swz >> 2;                        // 0..63
    const int bn = swz & 3;                         // 0..3
    const int tid = threadIdx.x;
    const int w = tid >> 6, lane = tid & 63;        // 8 waves
    const int wm = w & 1, wn = w >> 1;              // 2m x 4n
    const int lm = lane & 15, q = lane >> 4;

    f32x4 acc[8][4];
#pragma unroll
    for (int i = 0; i < 8; i++)
#pragma unroll
        for (int j = 0; j < 4; j++)
            acc[i][j] = (f32x4){0.0f, 0.0f, 0.0f, 0.0f};

    // A staging global offsets (elements) — verified geometry
    int goff[2][2];
#pragma unroll
    for (int h = 0; h < 2; h++)
#pragma unroll
        for (int p2 = 0; p2 < 2; p2++) {
            int ci = h * 1024 + (w * 2 + p2) * 64 + lane;
            int row = ci >> 3;
            int c = (ci & 7) ^ (row & 7);
            goff[h][p2] = row * GK + c * 8;
        }

    // A frag read base addresses (LDS bytes) — verified geometry:
    // afr[mi][kk] @ smem[buf][arow0 + mi*1024 + MH*4096 + aswz[kk]] (u16)
    // byte offset = base(buf) + 2*(arow0 + aswz[kk]) + mi*2048 + MH*8192
    const int arow0 = (wm * 128 + lm) * 64;
    const int aswz0 = (q ^ (lm & 7)) * 8;
    const int aswz1 = ((4 + q) ^ (lm & 7)) * 8;
    const u32 base0 = (u32)(size_t)(__attribute__((address_space(3))) void*)&smem[0][0];
    const u32 a0 = base0 + 2u * (u32)(arow0 + aswz0);
    const u32 a1 = base0 + 2u * (u32)(arow0 + aswz1);
    const u32 c0 = a0 + 32768u;                     // buf1 bases
    const u32 c1 = a1 + 32768u;

    const u16* Ab = A + (size_t)bm * 256 * GK;
    // packed-B wave base: c16 block = bn*16 + wn*4 (+nj); + lane chunk
    const u16* Bw = Bp + (size_t)(bn * 16 + wn * 4) * 16384 + lane * 8;

#define STAGE_A3(SB, TN) do {                                                 \
    const u16* gA_ = Ab + (TN) * 64;                                          \
    GLOAD_LDS16(gA_ + goff[0][0], (SB) + ((w * 2 + 0) * 64) * 8);             \
    GLOAD_LDS16(gA_ + goff[0][1], (SB) + ((w * 2 + 1) * 64) * 8);             \
    GLOAD_LDS16(gA_ + goff[1][0], (SB) + (1024 + (w * 2 + 0) * 64) * 8);      \
    GLOAD_LDS16(gA_ + goff[1][1], (SB) + (1024 + (w * 2 + 1) * 64) * 8);      \
} while (0)

#define LOAD_B(DST, T)                                                        \
    _Pragma("unroll") for (int nj = 0; nj < 4; nj++)                          \
    _Pragma("unroll") for (int kk = 0; kk < 2; kk++)                          \
        DST[nj][kk] = *(const bf16x8*)&Bw[nj * 16384 + ((T) * 2 + kk) * 512];

    // inline-asm ds_read_b128: opaque to the waitcnt pass (no alias drain)
#define DSR(D, AD, O) asm volatile("ds_read_b128 %0, %1 offset:" O          \
                                   : "=v"(D) : "v"(AD))

#define READ_HALF0(A0, A1, F) do {                                            \
    DSR(F[0][0], A0, "0");     DSR(F[0][1], A1, "0");                         \
    DSR(F[1][0], A0, "2048");  DSR(F[1][1], A1, "2048");                      \
    DSR(F[2][0], A0, "4096");  DSR(F[2][1], A1, "4096");                      \
    DSR(F[3][0], A0, "6144");  DSR(F[3][1], A1, "6144");                      \
} while (0)

#define READ_HALF1(A0, A1, F) do {                                            \
    DSR(F[0][0], A0, "8192");  DSR(F[0][1], A1, "8192");                      \
    DSR(F[1][0], A0, "10240"); DSR(F[1][1], A1, "10240");                     \
    DSR(F[2][0], A0, "12288"); DSR(F[2][1], A1, "12288");                     \
    DSR(F[3][0], A0, "14336"); DSR(F[3][1], A1, "14336");                     \
} while (0)

#define MFMA_HALF(MH, AF, BF)                                                 \
    _Pragma("unroll") for (int kk = 0; kk < 2; kk++)                          \
    _Pragma("unroll") for (int mi = 0; mi < 4; mi++)                          \
    _Pragma("unroll") for (int nj = 0; nj < 4; nj++)                          \
        acc[(MH) * 4 + mi][nj] = __builtin_amdgcn_mfma_f32_16x16x32_bf16(     \
            AF[mi][kk], BF[nj][kk], acc[(MH) * 4 + mi][nj], 0, 0, 0);

    // tile T: read (RD0,RD1) from cur buf; stage A(T+1)->STG; B(T+1)->BN;
    // compute with BC; end: vmcnt(8) certifies A(T+1), keeps B(T+1) live.
#define TILE(RD0, RD1, STG, BC, BN, T) do {                                   \
    if ((T) < NT - 1) {                                                       \
        STAGE_A3(STG, (T) + 1);                                               \
        LOAD_B(BN, (T) + 1);                                                  \
    }                                                                         \
    READ_HALF0(RD0, RD1, afrX);                                               \
    asm volatile("s_waitcnt lgkmcnt(0)" ::: "memory");                        \
    __builtin_amdgcn_sched_barrier(0);                                        \
    __builtin_amdgcn_s_setprio(1);                                            \
    MFMA_HALF(0, afrX, BC);                                                   \
    __builtin_amdgcn_s_setprio(0);                                            \
    READ_HALF1(RD0, RD1, afrY);                                               \
    asm volatile("s_waitcnt lgkmcnt(0)" ::: "memory");                        \
    __builtin_amdgcn_sched_barrier(0);                                        \
    __builtin_amdgcn_s_setprio(1);                                            \
    MFMA_HALF(1, afrY, BC);                                                   \
    __builtin_amdgcn_s_setprio(0);                                            \
    asm volatile("s_waitcnt vmcnt(8)" ::: "memory");                          \
    __builtin_amdgcn_sched_barrier(0);                                        \
    __builtin_amdgcn_s_barrier();                                             \
    __builtin_amdgcn_sched_barrier(0);                                        \
} while (0)

    bf16x8 afrX[4][2], afrY[4][2], bfA[4][2], bfB[4][2];

    // prologue: A(0)->buf0, B(0)->bfA; certify A(0) (leave B(0) in flight)
    STAGE_A3(&smem[0][0], 0);
    LOAD_B(bfA, 0);
    asm volatile("s_waitcnt vmcnt(8)" ::: "memory");
    __builtin_amdgcn_sched_barrier(0);
    __builtin_amdgcn_s_barrier();
    __builtin_amdgcn_sched_barrier(0);

    for (int tt = 0; tt < 8; ++tt) {
        const int t0 = 2 * tt, t1 = 2 * tt + 1;
        TILE(a0, a1, &smem[1][0], bfA, bfB, t0);   // even tile: buf0, B in bfA
        TILE(c0, c1, &smem[0][0], bfB, bfA, t1);   // odd tile:  buf1, B in bfB
    }

    asm volatile("s_waitcnt vmcnt(0)" ::: "memory");

#undef STAGE_A3
#undef LOAD_B
#undef DSR
#undef READ_HALF0
#undef READ_HALF1
#undef MFMA_HALF
#undef TILE

    // epilogue: s = sum_nfr v[nfr]*ssp(acc+bias[nfr]); 16-lane shfl reduce;
    // cross-wave (wn) combine in LDS (aliased over smem); store to parts.
    __syncthreads();
    float* red = (float*)&smem[0][0];               // [4][256]
    const bool is_q = (bn >= 2);
    const float* bb2 = is_q ? bc1 : b1;
    const float* vv = is_q ? Wc2 : W2;
    float bias[4], v[4];
#pragma unroll
    for (int nfr = 0; nfr < 4; nfr++) {
        int c = (bn & 1) * 256 + wn * 64 + nfr * 16 + lm;
        bias[nfr] = bb2[c];
        v[nfr] = vv[c];
    }
#pragma unroll
    for (int mfr = 0; mfr < 8; mfr++) {
#pragma unroll
        for (int r = 0; r < 4; r++) {
            float s = 0.0f;
#pragma unroll
            for (int nfr = 0; nfr < 4; nfr++)
                s += v[nfr] * ssp_f(acc[mfr][nfr][r] + bias[nfr]);
            s += __shfl_xor(s, 1);
            s += __shfl_xor(s, 2);
            s += __shfl_xor(s, 4);
            s += __shfl_xor(s, 8);
            if (lm == 0) red[wn * 256 + wm * 128 + mfr * 16 + q * 4 + r] = s;
        }
    }
    __syncthreads();
    if (tid < 256) {
        float val = red[0 * 256 + tid] + red[1 * 256 + tid] +
                    red[2 * 256 + tid] + red[3 * 256 + tid];
        parts[(size_t)bn * 16384 + bm * 256 + tid] = val;
    }
}

// ---------------- coulomb: 256 blocks (8 chunks x 32 batches) ----------------

__global__ __launch_bounds__(256) void coulomb_k(
    const float* __restrict__ R, const float* __restrict__ mask,
    const float* __restrict__ parts, const float* __restrict__ b2p,
    const float* __restrict__ bc2p, float* __restrict__ out)
{
    const int N = 512;
    const int b = blockIdx.y;
    const int chunk = blockIdx.x;
    __shared__ float Rx[512], Ry[512], Rz[512], QM[512];
    __shared__ float rbuf[4];
    const int tid = threadIdx.x;
    const float bc2 = bc2p[0];
    const float b2 = b2p[0];

    for (int j = tid; j < N; j += 256) {
        int idx = b * N + j;
        float m = mask[idx];
        const float* rp = R + (size_t)idx * 3;
        Rx[j] = rp[0];
        Ry[j] = rp[1];
        Rz[j] = rp[2];
        float qv = parts[2 * 16384 + idx] + parts[3 * 16384 + idx] + bc2;
        QM[j] = qv * m;
    }
    __syncthreads();

    const int i = chunk * 64 + (tid & 63);
    const int js = (tid >> 6) * 128;
    const float xi = Rx[i], yi = Ry[i], zi = Rz[i], qmi = QM[i];
    float e = 0.0f;
    for (int j = js; j < js + 128; j++) {
        float dx = xi - Rx[j];
        float dy = yi - Ry[j];
        float dz = zi - Rz[j];
        float d2 = dx * dx + dy * dy + dz * dz;
        float t = 1e-5f + sqrtf(d2);
        float term = qmi * QM[j] / (t * t);
        e += (j == i) ? 0.0f : term;
    }
    if (tid < 64) {
        int ii = b * N + chunk * 64 + tid;
        float yv = parts[0 * 16384 + ii] + parts[1 * 16384 + ii] + b2;
        e += yv * mask[ii];
    }
    for (int off = 32; off > 0; off >>= 1) e += __shfl_down(e, off, 64);
    if ((tid & 63) == 0) rbuf[tid >> 6] = e;
    __syncthreads();
    if (tid == 0) atomicAdd(&out[b], rbuf[0] + rbuf[1] + rbuf[2] + rbuf[3]);
}

// ---------------- fp32 fallback (R1) ----------------

#define BM 128
#define BN 64
#define BK 16

__global__ __launch_bounds__(256) void mlp_gemm(
    const float* __restrict__ A, const float* __restrict__ W1,
    const float* __restrict__ Wc1, const float* __restrict__ b1,
    const float* __restrict__ bc1, const float* __restrict__ W2,
    const float* __restrict__ Wc2, float* __restrict__ yi_part,
    float* __restrict__ q_part)
{
    const int K = 1024;
    const int bm = blockIdx.x;
    const int bn = blockIdx.y;
    const bool is_q = (bn >= 8);
    const float* __restrict__ W = is_q ? Wc1 : W1;
    const int j0 = (bn & 7) * BN;

    __shared__ float As[BK][BM + 4];
    __shared__ float Bs[BK][BN + 4];
    __shared__ float red[BM];

    const int tid = threadIdx.x;
    const int tx = tid & 15;
    const int ty = tid >> 4;

    float acc[8][4];
#pragma unroll
    for (int r = 0; r < 8; r++)
#pragma unroll
        for (int c = 0; c < 4; c++) acc[r][c] = 0.0f;

    const int a_row = tid >> 2;
    const int a_k4 = (tid & 3) * 4;
    const float* Arow0 = A + (size_t)(bm * BM + a_row) * K;
    const float* Arow1 = Arow0 + (size_t)64 * K;
    const int w_k = tid >> 4;
    const int w_j = (tid & 15) * 4;

    for (int kt = 0; kt < K; kt += BK) {
        float4 av0 = *(const float4*)(Arow0 + kt + a_k4);
        float4 av1 = *(const float4*)(Arow1 + kt + a_k4);
        float4 wv = *(const float4*)(W + (size_t)(kt + w_k) * 512 + j0 + w_j);
        __syncthreads();
        As[a_k4 + 0][a_row] = av0.x;
        As[a_k4 + 1][a_row] = av0.y;
        As[a_k4 + 2][a_row] = av0.z;
        As[a_k4 + 3][a_row] = av0.w;
        As[a_k4 + 0][a_row + 64] = av1.x;
        As[a_k4 + 1][a_row + 64] = av1.y;
        As[a_k4 + 2][a_row + 64] = av1.z;
        As[a_k4 + 3][a_row + 64] = av1.w;
        *(float4*)&Bs[w_k][w_j] = wv;
        __syncthreads();
#pragma unroll
        for (int kk = 0; kk < BK; kk++) {
            float4 a0v = *(const float4*)&As[kk][ty * 8];
            float4 a1v = *(const float4*)&As[kk][ty * 8 + 4];
            float4 bv = *(const float4*)&Bs[kk][tx * 4];
            float ar[8] = {a0v.x, a0v.y, a0v.z, a0v.w, a1v.x, a1v.y, a1v.z, a1v.w};
            float bc[4] = {bv.x, bv.y, bv.z, bv.w};
#pragma unroll
            for (int r = 0; r < 8; r++)
#pragma unroll
                for (int c = 0; c < 4; c++)
                    acc[r][c] = fmaf(ar[r], bc[c], acc[r][c]);
        }
    }

    const float* bb = is_q ? bc1 : b1;
    const float* vv = is_q ? Wc2 : W2;
    float bias[4], v[4];
#pragma unroll
    for (int c = 0; c < 4; c++) {
        bias[c] = bb[j0 + tx * 4 + c];
        v[c] = vv[j0 + tx * 4 + c];
    }
    if (tid < BM) red[tid] = 0.0f;
    __syncthreads();
#pragma unroll
    for (int r = 0; r < 8; r++) {
        float s = 0.0f;
#pragma unroll
        for (int c = 0; c < 4; c++)
            s += v[c] * ssp_slow(acc[r][c] + bias[c]);
        atomicAdd(&red[ty * 8 + r], s);
    }
    __syncthreads();
    float* target = is_q ? q_part : yi_part;
    if (tid < BM) atomicAdd(&target[(size_t)bm * BM + tid], red[tid]);
}

__global__ __launch_bounds__(256) void coulomb_fb(
    const float* __restrict__ R, const float* __restrict__ mask,
    const float* __restrict__ yi_part, const float* __restrict__ q_part,
    const float* __restrict__ b2p, const float* __restrict__ bc2p,
    float* __restrict__ out)
{
    const int N = 512;
    const int b = blockIdx.y;
    const int chunk = blockIdx.x;
    __shared__ float Rx[512], Ry[512], Rz[512], QM[512];
    __shared__ float rbuf[4];
    const int tid = threadIdx.x;
    const float bc2 = bc2p[0];
    const float b2 = b2p[0];

    for (int j = tid; j < N; j += 256) {
        float m = mask[b * N + j];
        const float* rp = R + ((size_t)b * N + j) * 3;
        Rx[j] = rp[0];
        Ry[j] = rp[1];
        Rz[j] = rp[2];
        QM[j] = (q_part[b * N + j] + bc2) * m;
    }
    __syncthreads();

    const int i = chunk * 64 + (tid & 63);
    const int js = (tid >> 6) * 128;
    const float xi = Rx[i], yi = Ry[i], zi = Rz[i], qmi = QM[i];
    float e = 0.0f;
    for (int j = js; j < js + 128; j++) {
        float dx = xi - Rx[j];
        float dy = yi - Ry[j];
        float dz = zi - Rz[j];
        float d2 = dx * dx + dy * dy + dz * dz;
        float t = 1e-5f + sqrtf(d2);
        float term = qmi * QM[j] / (t * t);
        e += (j == i) ? 0.0f : term;
    }
    if (tid < 64) {
        int ii = chunk * 64 + tid;
        e += (yi_part[b * N + ii] + b2) * mask[b * N + ii];
    }
    for (int off = 32; off > 0; off >>= 1) e += __shfl_down(e, off, 64);
    if ((tid & 63) == 0) rbuf[tid >> 6] = e;
    __syncthreads();
    if (tid == 0) atomicAdd(&out[b], rbuf[0] + rbuf[1] + rbuf[2] + rbuf[3]);
}

// ---------------- launch ----------------

extern "C" void kernel_launch(void* const* d_in, const int* in_sizes, int n_in,
                              void* d_out, int out_size, void* d_ws, size_t ws_size,
                              hipStream_t stream) {
    const float* rep  = (const float*)d_in[0];
    const float* R    = (const float*)d_in[1];
    const float* mask = (const float*)d_in[2];
    const float* W1   = (const float*)d_in[3];
    const float* b1   = (const float*)d_in[4];
    const float* W2   = (const float*)d_in[5];
    const float* b2   = (const float*)d_in[6];
    const float* Wc1  = (const float*)d_in[7];
    const float* bc1  = (const float*)d_in[8];
    const float* Wc2  = (const float*)d_in[9];
    const float* bc2  = (const float*)d_in[10];
    float* out = (float*)d_out;

    const size_t szA = 16384ull * 1024 * 2;   // 32 MB bf16 A
    const size_t szB = 1024ull * 1024 * 2;    // 2 MB packed bf16 B
    const size_t szP = 8ull * 16384 * 4;      // partials (4 used)
    const size_t need = szA + szB + szP;

    if (ws_size >= need) {
        u16* Abf = (u16*)d_ws;
        u16* Bpk = (u16*)((char*)d_ws + szA);
        float* parts = (float*)((char*)d_ws + szA + szB);

        prep<<<8192 + 1024, 256, 0, stream>>>(rep, W1, Wc1, Abf, Bpk, out);
        gemm_mfma<<<256, 512, 0, stream>>>(Abf, Bpk, b1, W2, bc1, Wc2, parts);
        coulomb_k<<<dim3(8, 32), 256, 0, stream>>>(R, mask, parts, b2, bc2, out);
    } else {
        float* yi_part = (float*)d_ws;
        float* q_part = yi_part + 16384;
        hipMemsetAsync(d_ws, 0, 2 * 16384 * sizeof(float), stream);
        hipMemsetAsync(d_out, 0, 32 * sizeof(float), stream);
        mlp_gemm<<<dim3(128, 16), 256, 0, stream>>>(rep, W1, Wc1, b1, bc1, W2, Wc2,
                                                    yi_part, q_part);
        coulomb_fb<<<dim3(8, 32), 256, 0, stream>>>(R, mask, yi_part, q_part, b2, bc2, out);
    }
}

// Round 10
// 168.482 us; speedup vs baseline: 1.0204x; 1.0204x over previous
//
#include <hip/hip_runtime.h>
#include <math.h>

// EnergyCoulomb: B=32, N=512, D=1024, H=512
// R20: 256x256 GEMM, BK=64 — the untested cell: FINE 3-phase schedule
//      (m201 template) + COUNTED vmcnt(4) + ASM ds_reads.
//      m196: coarse phase-split ~= 1-phase (explains R12..R19 plateau);
//      m218: counted-vs-drain pays +38-73% only inside fine phases;
//      R14's collapse = compiler ds_reads let waitcnt pass re-insert
//      drains -> asm reads required (R19 machinery, verified correct).
//      Half-certification requires stage-half == frag-half: global source
//      rows permuted per-lane (A: swap row bits 6,7; B: rotate bits 5-7)
//      so gload group h lands exactly frag-half h. LDS dest stays linear
//      (gload_lds constraint); read swizzle (row&7) unaffected (low bits
//      preserved). Hand-verified A/B sample coords end-to-end.
//      Per tile: P0{stage A-h0' | read A0+B0 | bar | lgkm0 | Q00 | vmcnt(4)
//      | bar}, P1{stage B-h0' | read B1 | ... Q01 ...}, P2{stage B-h1',
//      A-h1' | read A1 | ... Q11+Q10 ...}. FIFO: >=4 in flight always,
//      certified loads >=1.5 phases old. Never drains in loop.
//      prep reverts to R11's verified Btb writer; coulomb unchanged.

typedef unsigned short u16;
typedef unsigned int u32;
typedef __bf16 bf16x8 __attribute__((ext_vector_type(8)));
typedef float f32x4 __attribute__((ext_vector_type(4)));

#define GK 1024
#define NT 16

#define GLOAD_LDS16(g, l) __builtin_amdgcn_global_load_lds( \
    (const __attribute__((address_space(1))) void*)(g),     \
    (__attribute__((address_space(3))) void*)(l), 16, 0, 0)

__device__ __forceinline__ u16 f2bf(float f) {
    u32 u = __float_as_uint(f);
    return (u16)((u + 0x7FFFu + ((u >> 16) & 1u)) >> 16);
}

__device__ __forceinline__ float ssp_f(float x) {
    return __logf(0.5f * (__expf(x) + 1.0f));
}

__device__ __forceinline__ float ssp_slow(float x) {
    return fmaxf(x, 0.0f) + log1pf(expf(-fabsf(x))) - 0.6931471805599453f;
}

// ---------------- prep: conv_a + conv_w + out zero (R3/R11-verified) ------

__global__ __launch_bounds__(256) void prep(
    const float* __restrict__ rep, const float* __restrict__ W1,
    const float* __restrict__ Wc1, u16* __restrict__ Abf,
    u16* __restrict__ Btb, float* __restrict__ out)
{
    __shared__ float tile[32][33];
    const int blk = blockIdx.x;
    const int t = threadIdx.x;
    if (blk < 8192) {
        int i = (blk * 256 + t) * 8;
        float4 x = *(const float4*)(rep + i);
        float4 y = *(const float4*)(rep + i + 4);
        union { u16 h[8]; uint4 v; } o;
        o.h[0] = f2bf(x.x); o.h[1] = f2bf(x.y); o.h[2] = f2bf(x.z); o.h[3] = f2bf(x.w);
        o.h[4] = f2bf(y.x); o.h[5] = f2bf(y.y); o.h[6] = f2bf(y.z); o.h[7] = f2bf(y.w);
        *(uint4*)(Abf + i) = o.v;
        if (blk == 0 && t < 32) out[t] = 0.0f;
    } else {
        const int bb = blk - 8192;                  // 0..1023
        const int k0 = (bb & 31) * 32;
        const int n0 = (bb >> 5) * 32;              // 0..1023
        const float* src = (n0 < 512) ? W1 : Wc1;
        const int ns0 = (n0 < 512) ? n0 : n0 - 512;
#pragma unroll
        for (int j = 0; j < 4; j++) {
            int idx = j * 256 + t;
            int kl = idx >> 5, nl = idx & 31;
            tile[kl][nl] = src[(size_t)(k0 + kl) * 512 + ns0 + nl];
        }
        __syncthreads();
#pragma unroll
        for (int j = 0; j < 4; j++) {
            int idx = j * 256 + t;
            int nl = idx >> 5, kl = idx & 31;
            Btb[(size_t)(n0 + nl) * 1024 + k0 + kl] = f2bf(tile[kl][nl]);
        }
    }
}

// ---- bf16 MFMA GEMM: 256x256, BK=64, fine 3-phase counted pipeline ----

__global__ __launch_bounds__(512, 2) void gemm_mfma(
    const u16* __restrict__ A,    // [16384][1024] bf16
    const u16* __restrict__ Bt,   // [1024][1024] bf16
    const float* __restrict__ b1, const float* __restrict__ W2,
    const float* __restrict__ bc1, const float* __restrict__ Wc2,
    float* __restrict__ parts)    // [4][16384]
{
    __shared__ u16 smem[2][32768];                  // 128 KiB: [buf][A | B]

    const int blk = blockIdx.x;                     // 0..255
    const int swz = ((blk & 7) << 5) | (blk >> 3);
    const int bm = swz >> 2;                        // 0..63
    const int bn = swz & 3;                         // 0..3
    const int tid = threadIdx.x;
    const int w = tid >> 6, lane = tid & 63;        // 8 waves
    const int wm = w & 1, wn = w >> 1;              // 2m x 4n
    const int lm = lane & 15, q = lane >> 4;

    f32x4 acc[8][4];
#pragma unroll
    for (int i = 0; i < 8; i++)
#pragma unroll
        for (int j = 0; j < 4; j++)
            acc[i][j] = (f32x4){0.0f, 0.0f, 0.0f, 0.0f};

    // staging source offsets with half-aligning row permutation:
    // slot s = ci>>3; A src row = swap bits6,7 of s; B src row = rotate
    // (s5->wn-low? exactly: gB = (s&31) + ((s>>5)&3)*64 + ((s>>7)&1)*32).
    // phys chunk c = (ci&7)^(s&7) (verified XOR swizzle, low bits of s
    // unchanged by the permutations).
    int goffA[2][2], goffB[2][2];
#pragma unroll
    for (int h = 0; h < 2; h++)
#pragma unroll
        for (int p2 = 0; p2 < 2; p2++) {
            int ci = h * 1024 + (w * 2 + p2) * 64 + lane;
            int s = ci >> 3;
            int c = (ci & 7) ^ (s & 7);
            int gA = (s & 63) + ((s >> 6) & 1) * 128 + ((s >> 7) & 1) * 64;
            int gB = (s & 31) + ((s >> 5) & 3) * 64 + ((s >> 7) & 1) * 32;
            goffA[h][p2] = gA * GK + c * 8;
            goffB[h][p2] = gB * GK + c * 8;
        }

    // frag read byte bases (slot layout: A row-slot = MH*128+wm*64+mi*16+lm,
    // B row-slot = NH*128+wn*32+nj*16+lm; 128 B per row; swizzle on slot&7=lm&7)
    const int aswz0 = (q ^ (lm & 7)) * 8;
    const int aswz1 = ((4 + q) ^ (lm & 7)) * 8;
    const u32 base0 = (u32)(size_t)(__attribute__((address_space(3))) void*)&smem[0][0];
    const u32 aA0 = base0 + 2u * (u32)((wm * 64 + lm) * 64 + aswz0);
    const u32 aA1 = base0 + 2u * (u32)((wm * 64 + lm) * 64 + aswz1);
    const u32 bB0 = base0 + 32768u + 2u * (u32)((wn * 32 + lm) * 64 + aswz0);
    const u32 bB1 = base0 + 32768u + 2u * (u32)((wn * 32 + lm) * 64 + aswz1);
    const u32 aA0b = aA0 + 65536u, aA1b = aA1 + 65536u;
    const u32 bB0b = bB0 + 65536u, bB1b = bB1 + 65536u;

    const u16* Ab = A + (size_t)bm * 256 * GK;
    const u16* Bb = Bt + (size_t)bn * 256 * GK;

#define STAGE2(G, RG, H, BUF, GOFF) do {                                      \
    GLOAD_LDS16((G) + GOFF[H][0], &smem[BUF][(RG) + ((H) * 1024 + (w * 2 + 0) * 64) * 8]); \
    GLOAD_LDS16((G) + GOFF[H][1], &smem[BUF][(RG) + ((H) * 1024 + (w * 2 + 1) * 64) * 8]); \
} while (0)

#define DSR(D, AD, O) asm volatile("ds_read_b128 %0, %1 offset:" #O          \
                                   : "=v"(D) : "v"(AD))

#define RD_A0(F, R0, R1) do {                                                 \
    DSR(F[0][0], R0, 0);     DSR(F[0][1], R1, 0);                             \
    DSR(F[1][0], R0, 2048);  DSR(F[1][1], R1, 2048);                          \
    DSR(F[2][0], R0, 4096);  DSR(F[2][1], R1, 4096);                          \
    DSR(F[3][0], R0, 6144);  DSR(F[3][1], R1, 6144); } while (0)

#define RD_A1(F, R0, R1) do {                                                 \
    DSR(F[0][0], R0, 16384); DSR(F[0][1], R1, 16384);                         \
    DSR(F[1][0], R0, 18432); DSR(F[1][1], R1, 18432);                         \
    DSR(F[2][0], R0, 20480); DSR(F[2][1], R1, 20480);                         \
    DSR(F[3][0], R0, 22528); DSR(F[3][1], R1, 22528); } while (0)

#define RD_B0(F, R0, R1) do {                                                 \
    DSR(F[0][0], R0, 0);     DSR(F[0][1], R1, 0);                             \
    DSR(F[1][0], R0, 2048);  DSR(F[1][1], R1, 2048); } while (0)

#define RD_B1(F, R0, R1) do {                                                 \
    DSR(F[0][0], R0, 16384); DSR(F[0][1], R1, 16384);                         \
    DSR(F[1][0], R0, 18432); DSR(F[1][1], R1, 18432); } while (0)

#define MFMA_Q(MH, NH, AF, BF)                                                \
    _Pragma("unroll") for (int kk = 0; kk < 2; kk++)                          \
    _Pragma("unroll") for (int mi = 0; mi < 4; mi++)                          \
    _Pragma("unroll") for (int nj = 0; nj < 2; nj++)                          \
        acc[(MH) * 4 + mi][(NH) * 2 + nj] = __builtin_amdgcn_mfma_f32_16x16x32_bf16( \
            AF[mi][kk], BF[nj][kk], acc[(MH) * 4 + mi][(NH) * 2 + nj], 0, 0, 0);

#define WAITV4 do { asm volatile("s_waitcnt vmcnt(4)" ::: "memory");          \
                    __builtin_amdgcn_sched_barrier(0); } while (0)
#define LGKM0  do { asm volatile("s_waitcnt lgkmcnt(0)" ::: "memory");        \
                    __builtin_amdgcn_sched_barrier(0); } while (0)

    // tile: read from bases (RA0,RA1,RB0,RB1); stage tile t+1 into SB.
#define TILE(RA0, RA1, RB0, RB1, SB, GAN, GBN) do {                           \
    /* P0: Q00 */                                                             \
    STAGE2(GAN, 0, 0, SB, goffA);                                             \
    RD_A0(afr, RA0, RA1);                                                     \
    RD_B0(b0f, RB0, RB1);                                                     \
    __builtin_amdgcn_s_barrier();                                             \
    LGKM0;                                                                    \
    __builtin_amdgcn_s_setprio(1);                                            \
    MFMA_Q(0, 0, afr, b0f);                                                   \
    __builtin_amdgcn_s_setprio(0);                                            \
    WAITV4;                                                                   \
    __builtin_amdgcn_s_barrier();                                             \
    /* P1: Q01 */                                                             \
    STAGE2(GBN, 16384, 0, SB, goffB);                                         \
    RD_B1(b1f, RB0, RB1);                                                     \
    __builtin_amdgcn_s_barrier();                                             \
    LGKM0;                                                                    \
    __builtin_amdgcn_s_setprio(1);                                            \
    MFMA_Q(0, 1, afr, b1f);                                                   \
    __builtin_amdgcn_s_setprio(0);                                            \
    WAITV4;                                                                   \
    __builtin_amdgcn_s_barrier();                                             \
    /* P2: Q11 + Q10 */                                                       \
    STAGE2(GBN, 16384, 1, SB, goffB);                                         \
    STAGE2(GAN, 0, 1, SB, goffA);                                             \
    RD_A1(afr, RA0, RA1);                                                     \
    __builtin_amdgcn_s_barrier();                                             \
    LGKM0;                                                                    \
    __builtin_amdgcn_s_setprio(1);                                            \
    MFMA_Q(1, 1, afr, b1f);                                                   \
    MFMA_Q(1, 0, afr, b0f);                                                   \
    __builtin_amdgcn_s_setprio(0);                                            \
    WAITV4;                                                                   \
    __builtin_amdgcn_s_barrier();                                             \
} while (0)

    bf16x8 afr[4][2], b0f[2][2], b1f[2][2];

    // prologue: stage tile 0 halves in order A-h0,B-h0,B-h1,A-h1 (8 loads);
    // certify the first two halves; leave B-h1,A-h1 in flight (steady entry).
    STAGE2(Ab, 0, 0, 0, goffA);
    STAGE2(Bb, 16384, 0, 0, goffB);
    STAGE2(Bb, 16384, 1, 0, goffB);
    STAGE2(Ab, 0, 1, 0, goffA);
    WAITV4;
    __builtin_amdgcn_s_barrier();

    for (int tt = 0; tt < 8; ++tt) {
        const u16* gA0 = Ab + ((2 * tt + 1) & (NT - 1)) * 64;
        const u16* gB0 = Bb + ((2 * tt + 1) & (NT - 1)) * 64;
        const u16* gA1 = Ab + ((2 * tt + 2) & (NT - 1)) * 64;
        const u16* gB1 = Bb + ((2 * tt + 2) & (NT - 1)) * 64;
        TILE(aA0, aA1, bB0, bB1, 1, gA0, gB0);      // even: read buf0, stage buf1
        TILE(aA0b, aA1b, bB0b, bB1b, 0, gA1, gB1);  // odd: read buf1, stage buf0
    }

    asm volatile("s_waitcnt vmcnt(0)" ::: "memory");

#undef STAGE2
#undef DSR
#undef RD_A0
#undef RD_A1
#undef RD_B0
#undef RD_B1
#undef MFMA_Q
#undef WAITV4
#undef LGKM0
#undef TILE

    // epilogue: s = sum_nfr v[nfr]*ssp(acc+bias[nfr]); 16-lane shfl reduce;
    // cross-wave (wn) combine in LDS (aliased over smem); store to parts.
    __syncthreads();
    float* red = (float*)&smem[0][0];               // [4][256]
    const bool is_q = (bn >= 2);
    const float* bb2 = is_q ? bc1 : b1;
    const float* vv = is_q ? Wc2 : W2;
    float bias[4], v[4];
#pragma unroll
    for (int nfr = 0; nfr < 4; nfr++) {
        int c = (bn & 1) * 256 + wn * 64 + nfr * 16 + lm;
        bias[nfr] = bb2[c];
        v[nfr] = vv[c];
    }
#pragma unroll
    for (int mfr = 0; mfr < 8; mfr++) {
#pragma unroll
        for (int r = 0; r < 4; r++) {
            float s = 0.0f;
#pragma unroll
            for (int nfr = 0; nfr < 4; nfr++)
                s += v[nfr] * ssp_f(acc[mfr][nfr][r] + bias[nfr]);
            s += __shfl_xor(s, 1);
            s += __shfl_xor(s, 2);
            s += __shfl_xor(s, 4);
            s += __shfl_xor(s, 8);
            if (lm == 0) red[wn * 256 + wm * 128 + mfr * 16 + q * 4 + r] = s;
        }
    }
    __syncthreads();
    if (tid < 256) {
        float val = red[0 * 256 + tid] + red[1 * 256 + tid] +
                    red[2 * 256 + tid] + red[3 * 256 + tid];
        parts[(size_t)bn * 16384 + bm * 256 + tid] = val;
    }
}

// ---------------- coulomb: 256 blocks (8 chunks x 32 batches) ----------------

__global__ __launch_bounds__(256) void coulomb_k(
    const float* __restrict__ R, const float* __restrict__ mask,
    const float* __restrict__ parts, const float* __restrict__ b2p,
    const float* __restrict__ bc2p, float* __restrict__ out)
{
    const int N = 512;
    const int b = blockIdx.y;
    const int chunk = blockIdx.x;
    __shared__ float Rx[512], Ry[512], Rz[512], QM[512];
    __shared__ float rbuf[4];
    const int tid = threadIdx.x;
    const float bc2 = bc2p[0];
    const float b2 = b2p[0];

    for (int j = tid; j < N; j += 256) {
        int idx = b * N + j;
        float m = mask[idx];
        const float* rp = R + (size_t)idx * 3;
        Rx[j] = rp[0];
        Ry[j] = rp[1];
        Rz[j] = rp[2];
        float qv = parts[2 * 16384 + idx] + parts[3 * 16384 + idx] + bc2;
        QM[j] = qv * m;
    }
    __syncthreads();

    const int i = chunk * 64 + (tid & 63);
    const int js = (tid >> 6) * 128;
    const float xi = Rx[i], yi = Ry[i], zi = Rz[i], qmi = QM[i];
    float e = 0.0f;
    for (int j = js; j < js + 128; j++) {
        float dx = xi - Rx[j];
        float dy = yi - Ry[j];
        float dz = zi - Rz[j];
        float d2 = dx * dx + dy * dy + dz * dz;
        float t = 1e-5f + sqrtf(d2);
        float term = qmi * QM[j] / (t * t);
        e += (j == i) ? 0.0f : term;
    }
    if (tid < 64) {
        int ii = b * N + chunk * 64 + tid;
        float yv = parts[0 * 16384 + ii] + parts[1 * 16384 + ii] + b2;
        e += yv * mask[ii];
    }
    for (int off = 32; off > 0; off >>= 1) e += __shfl_down(e, off, 64);
    if ((tid & 63) == 0) rbuf[tid >> 6] = e;
    __syncthreads();
    if (tid == 0) atomicAdd(&out[b], rbuf[0] + rbuf[1] + rbuf[2] + rbuf[3]);
}

// ---------------- fp32 fallback (R1) ----------------

#define BM 128
#define BN 64
#define BK 16

__global__ __launch_bounds__(256) void mlp_gemm(
    const float* __restrict__ A, const float* __restrict__ W1,
    const float* __restrict__ Wc1, const float* __restrict__ b1,
    const float* __restrict__ bc1, const float* __restrict__ W2,
    const float* __restrict__ Wc2, float* __restrict__ yi_part,
    float* __restrict__ q_part)
{
    const int K = 1024;
    const int bm = blockIdx.x;
    const int bn = blockIdx.y;
    const bool is_q = (bn >= 8);
    const float* __restrict__ W = is_q ? Wc1 : W1;
    const int j0 = (bn & 7) * BN;

    __shared__ float As[BK][BM + 4];
    __shared__ float Bs[BK][BN + 4];
    __shared__ float red[BM];

    const int tid = threadIdx.x;
    const int tx = tid & 15;
    const int ty = tid >> 4;

    float acc[8][4];
#pragma unroll
    for (int r = 0; r < 8; r++)
#pragma unroll
        for (int c = 0; c < 4; c++) acc[r][c] = 0.0f;

    const int a_row = tid >> 2;
    const int a_k4 = (tid & 3) * 4;
    const float* Arow0 = A + (size_t)(bm * BM + a_row) * K;
    const float* Arow1 = Arow0 + (size_t)64 * K;
    const int w_k = tid >> 4;
    const int w_j = (tid & 15) * 4;

    for (int kt = 0; kt < K; kt += BK) {
        float4 av0 = *(const float4*)(Arow0 + kt + a_k4);
        float4 av1 = *(const float4*)(Arow1 + kt + a_k4);
        float4 wv = *(const float4*)(W + (size_t)(kt + w_k) * 512 + j0 + w_j);
        __syncthreads();
        As[a_k4 + 0][a_row] = av0.x;
        As[a_k4 + 1][a_row] = av0.y;
        As[a_k4 + 2][a_row] = av0.z;
        As[a_k4 + 3][a_row] = av0.w;
        As[a_k4 + 0][a_row + 64] = av1.x;
        As[a_k4 + 1][a_row + 64] = av1.y;
        As[a_k4 + 2][a_row + 64] = av1.z;
        As[a_k4 + 3][a_row + 64] = av1.w;
        *(float4*)&Bs[w_k][w_j] = wv;
        __syncthreads();
#pragma unroll
        for (int kk = 0; kk < BK; kk++) {
            float4 a0v = *(const float4*)&As[kk][ty * 8];
            float4 a1v = *(const float4*)&As[kk][ty * 8 + 4];
            float4 bv = *(const float4*)&Bs[kk][tx * 4];
            float ar[8] = {a0v.x, a0v.y, a0v.z, a0v.w, a1v.x, a1v.y, a1v.z, a1v.w};
            float bc[4] = {bv.x, bv.y, bv.z, bv.w};
#pragma unroll
            for (int r = 0; r < 8; r++)
#pragma unroll
                for (int c = 0; c < 4; c++)
                    acc[r][c] = fmaf(ar[r], bc[c], acc[r][c]);
        }
    }

    const float* bb = is_q ? bc1 : b1;
    const float* vv = is_q ? Wc2 : W2;
    float bias[4], v[4];
#pragma unroll
    for (int c = 0; c < 4; c++) {
        bias[c] = bb[j0 + tx * 4 + c];
        v[c] = vv[j0 + tx * 4 + c];
    }
    if (tid < BM) red[tid] = 0.0f;
    __syncthreads();
#pragma unroll
    for (int r = 0; r < 8; r++) {
        float s = 0.0f;
#pragma unroll
        for (int c = 0; c < 4; c++)
            s += v[c] * ssp_slow(acc[r][c] + bias[c]);
        atomicAdd(&red[ty * 8 + r], s);
    }
    __syncthreads();
    float* target = is_q ? q_part : yi_part;
    if (tid < BM) atomicAdd(&target[(size_t)bm * BM + tid], red[tid]);
}

__global__ __launch_bounds__(256) void coulomb_fb(
    const float* __restrict__ R, const float* __restrict__ mask,
    const float* __restrict__ yi_part, const float* __restrict__ q_part,
    const float* __restrict__ b2p, const float* __restrict__ bc2p,
    float* __restrict__ out)
{
    const int N = 512;
    const int b = blockIdx.y;
    const int chunk = blockIdx.x;
    __shared__ float Rx[512], Ry[512], Rz[512], QM[512];
    __shared__ float rbuf[4];
    const int tid = threadIdx.x;
    const float bc2 = bc2p[0];
    const float b2 = b2p[0];

    for (int j = tid; j < N; j += 256) {
        float m = mask[b * N + j];
        const float* rp = R + ((size_t)b * N + j) * 3;
        Rx[j] = rp[0];
        Ry[j] = rp[1];
        Rz[j] = rp[2];
        QM[j] = (q_part[b * N + j] + bc2) * m;
    }
    __syncthreads();

    const int i = chunk * 64 + (tid & 63);
    const int js = (tid >> 6) * 128;
    const float xi = Rx[i], yi = Ry[i], zi = Rz[i], qmi = QM[i];
    float e = 0.0f;
    for (int j = js; j < js + 128; j++) {
        float dx = xi - Rx[j];
        float dy = yi - Ry[j];
        float dz = zi - Rz[j];
        float d2 = dx * dx + dy * dy + dz * dz;
        float t = 1e-5f + sqrtf(d2);
        float term = qmi * QM[j] / (t * t);
        e += (j == i) ? 0.0f : term;
    }
    if (tid < 64) {
        int ii = chunk * 64 + tid;
        e += (yi_part[b * N + ii] + b2) * mask[b * N + ii];
    }
    for (int off = 32; off > 0; off >>= 1) e += __shfl_down(e, off, 64);
    if ((tid & 63) == 0) rbuf[tid >> 6] = e;
    __syncthreads();
    if (tid == 0) atomicAdd(&out[b], rbuf[0] + rbuf[1] + rbuf[2] + rbuf[3]);
}

// ---------------- launch ----------------

extern "C" void kernel_launch(void* const* d_in, const int* in_sizes, int n_in,
                              void* d_out, int out_size, void* d_ws, size_t ws_size,
                              hipStream_t stream) {
    const float* rep  = (const float*)d_in[0];
    const float* R    = (const float*)d_in[1];
    const float* mask = (const float*)d_in[2];
    const float* W1   = (const float*)d_in[3];
    const float* b1   = (const float*)d_in[4];
    const float* W2   = (const float*)d_in[5];
    const float* b2   = (const float*)d_in[6];
    const float* Wc1  = (const float*)d_in[7];
    const float* bc1  = (const float*)d_in[8];
    const float* Wc2  = (const float*)d_in[9];
    const float* bc2  = (const float*)d_in[10];
    float* out = (float*)d_out;

    const size_t szA = 16384ull * 1024 * 2;   // 32 MB bf16 A
    const size_t szB = 1024ull * 1024 * 2;    // 2 MB bf16 Bt
    const size_t szP = 8ull * 16384 * 4;      // partials (4 used)
    const size_t need = szA + szB + szP;

    if (ws_size >= need) {
        u16* Abf = (u16*)d_ws;
        u16* Btb = (u16*)((char*)d_ws + szA);
        float* parts = (float*)((char*)d_ws + szA + szB);

        prep<<<8192 + 1024, 256, 0, stream>>>(rep, W1, Wc1, Abf, Btb, out);
        gemm_mfma<<<256, 512, 0, stream>>>(Abf, Btb, b1, W2, bc1, Wc2, parts);
        coulomb_k<<<dim3(8, 32), 256, 0, stream>>>(R, mask, parts, b2, bc2, out);
    } else {
        float* yi_part = (float*)d_ws;
        float* q_part = yi_part + 16384;
        hipMemsetAsync(d_ws, 0, 2 * 16384 * sizeof(float), stream);
        hipMemsetAsync(d_out, 0, 32 * sizeof(float), stream);
        mlp_gemm<<<dim3(128, 16), 256, 0, stream>>>(rep, W1, Wc1, b1, bc1, W2, Wc2,
                                                    yi_part, q_part);
        coulomb_fb<<<dim3(8, 32), 256, 0, stream>>>(R, mask, yi_part, q_part, b2, bc2, out);
    }
}

// Round 11
// 167.035 us; speedup vs baseline: 1.0292x; 1.0087x over previous
//
#include <hip/hip_runtime.h>
#include <math.h>

// EnergyCoulomb: B=32, N=512, D=1024, H=512
// R21: 256x256 GEMM, BK=64 — faithful m201 8-phase stream.
//      Diagnosis: R11-R20 all 1 block/CU; every variant either drained
//      vmcnt per tile or certified ~1-phase-old loads. m201 (same
//      geometry, 1 blk/CU) sustains 20 B/cy/CU via: 4 even phases/tile,
//      stage stream 3-6 phases AHEAD of consumption, ONE vmcnt(6)/tile.
//      LDS: buf[2] x {A0,A1,B0,B1} halves (16KB each). Stream: tile t
//      P1 stages t+1.A1 -> buf[nxt] (free); P3 stages t+2.B0, P4 stages
//      t+2.B1 + t+2.A0 -> buf[cur] regions just freed (B read only in
//      P1/P2, A in P1/P3; stages issue after the freeing barrier).
//      vmcnt(6) at P4: FIFO => certifies all 4 halves of t+1 (ages 3-5
//      phases) and leaves exactly t+2's 3 halves (6 loads) in flight.
//      Phases: {asm ds_reads | stage | s_barrier | lgkm0+schedbar |
//      setprio1 16 MFMA setprio0 | s_barrier}; P4 has no reads:
//      {stages | MFMA | vmcnt(6) | s_barrier}. Never drains in loop.
//      Quadrant order (0,0)->(0,1)->(1,1)->(1,0); b0f lives P1..P4.
//      prep/coulomb/fallback unchanged (R11-verified).

typedef unsigned short u16;
typedef unsigned int u32;
typedef __bf16 bf16x8 __attribute__((ext_vector_type(8)));
typedef float f32x4 __attribute__((ext_vector_type(4)));

#define GK 1024
#define NT 16

#define GLOAD_LDS16(g, l) __builtin_amdgcn_global_load_lds( \
    (const __attribute__((address_space(1))) void*)(g),     \
    (__attribute__((address_space(3))) void*)(l), 16, 0, 0)

__device__ __forceinline__ u16 f2bf(float f) {
    u32 u = __float_as_uint(f);
    return (u16)((u + 0x7FFFu + ((u >> 16) & 1u)) >> 16);
}

__device__ __forceinline__ float ssp_f(float x) {
    return __logf(0.5f * (__expf(x) + 1.0f));
}

__device__ __forceinline__ float ssp_slow(float x) {
    return fmaxf(x, 0.0f) + log1pf(expf(-fabsf(x))) - 0.6931471805599453f;
}

// ---------------- prep: conv_a + conv_w + out zero (R3/R11-verified) ------

__global__ __launch_bounds__(256) void prep(
    const float* __restrict__ rep, const float* __restrict__ W1,
    const float* __restrict__ Wc1, u16* __restrict__ Abf,
    u16* __restrict__ Btb, float* __restrict__ out)
{
    __shared__ float tile[32][33];
    const int blk = blockIdx.x;
    const int t = threadIdx.x;
    if (blk < 8192) {
        int i = (blk * 256 + t) * 8;
        float4 x = *(const float4*)(rep + i);
        float4 y = *(const float4*)(rep + i + 4);
        union { u16 h[8]; uint4 v; } o;
        o.h[0] = f2bf(x.x); o.h[1] = f2bf(x.y); o.h[2] = f2bf(x.z); o.h[3] = f2bf(x.w);
        o.h[4] = f2bf(y.x); o.h[5] = f2bf(y.y); o.h[6] = f2bf(y.z); o.h[7] = f2bf(y.w);
        *(uint4*)(Abf + i) = o.v;
        if (blk == 0 && t < 32) out[t] = 0.0f;
    } else {
        const int bb = blk - 8192;                  // 0..1023
        const int k0 = (bb & 31) * 32;
        const int n0 = (bb >> 5) * 32;              // 0..1023
        const float* src = (n0 < 512) ? W1 : Wc1;
        const int ns0 = (n0 < 512) ? n0 : n0 - 512;
#pragma unroll
        for (int j = 0; j < 4; j++) {
            int idx = j * 256 + t;
            int kl = idx >> 5, nl = idx & 31;
            tile[kl][nl] = src[(size_t)(k0 + kl) * 512 + ns0 + nl];
        }
        __syncthreads();
#pragma unroll
        for (int j = 0; j < 4; j++) {
            int idx = j * 256 + t;
            int nl = idx >> 5, kl = idx & 31;
            Btb[(size_t)(n0 + nl) * 1024 + k0 + kl] = f2bf(tile[kl][nl]);
        }
    }
}

// ---- bf16 MFMA GEMM: 256x256, BK=64, m201-stream 4-phase pipeline ----

__global__ __launch_bounds__(512, 2) void gemm_mfma(
    const u16* __restrict__ A,    // [16384][1024] bf16
    const u16* __restrict__ Bt,   // [1024][1024] bf16
    const float* __restrict__ b1, const float* __restrict__ W2,
    const float* __restrict__ bc1, const float* __restrict__ Wc2,
    float* __restrict__ parts)    // [4][16384]
{
    __shared__ u16 smem[2][32768];                  // 128 KiB: buf x {A0,A1,B0,B1}

    const int blk = blockIdx.x;                     // 0..255
    const int swz = ((blk & 7) << 5) | (blk >> 3);
    const int bm = swz >> 2;                        // 0..63
    const int bn = swz & 3;                         // 0..3
    const int tid = threadIdx.x;
    const int w = tid >> 6, lane = tid & 63;        // 8 waves
    const int wm = w & 1, wn = w >> 1;              // 2m x 4n
    const int lm = lane & 15, q = lane >> 4;

    f32x4 acc[8][4];
#pragma unroll
    for (int i = 0; i < 8; i++)
#pragma unroll
        for (int j = 0; j < 4; j++)
            acc[i][j] = (f32x4){0.0f, 0.0f, 0.0f, 0.0f};

    // staging source offsets within a half-tile (1024 chunks of 16B):
    // chunk ci=(w*2+p2)*64+lane; slot s=ci>>3 (row-in-half, 0..127);
    // logical k-chunk c=(ci&7)^(s&7) (verified XOR swizzle).
    int soff[2];
#pragma unroll
    for (int p2 = 0; p2 < 2; p2++) {
        int ci = (w * 2 + p2) * 64 + lane;
        int s = ci >> 3;
        int c = (ci & 7) ^ (s & 7);
        soff[p2] = s * GK + c * 8;
    }

    // frag read byte bases. Buffer regions (bytes): A0@0 A1@16384
    // B0@32768 B1@49152. Row-in-half r: A r=qm*64+mi*16+lm (half=wm),
    // B r=(wn&1)*64+qn*32+nj*16+lm (half=wn>>1). r&7==lm&7.
    const int swz0 = (q ^ (lm & 7)) * 16;
    const int swz1 = ((4 + q) ^ (lm & 7)) * 16;
    const u32 base0 = (u32)(size_t)(__attribute__((address_space(3))) void*)&smem[0][0];
    const u32 xA0 = base0 + (u32)(wm * 16384 + lm * 128 + swz0);
    const u32 xA1 = base0 + (u32)(wm * 16384 + lm * 128 + swz1);
    const u32 xB0 = base0 + (u32)(32768 + (wn >> 1) * 16384 + ((wn & 1) * 64 + lm) * 128 + swz0);
    const u32 xB1 = base0 + (u32)(32768 + (wn >> 1) * 16384 + ((wn & 1) * 64 + lm) * 128 + swz1);
    const u32 yA0 = xA0 + 65536u, yA1 = xA1 + 65536u;
    const u32 yB0 = xB0 + 65536u, yB1 = xB1 + 65536u;

    const u16* Ab = A + (size_t)bm * 256 * GK;
    const u16* Bb = Bt + (size_t)bn * 256 * GK;

    // stage half H (A via G=Ab / B via G=Bb) of k-tile T into buf BUF
    // region REGU16 (u16 units: A0=0, A1=8192, B0=16384, B1=24576)
#define STAGE_H(G, T, H, BUF, REGU16) do {                                    \
    const u16* g_ = (G) + (size_t)(H) * 128 * GK + (size_t)(T) * 64;          \
    GLOAD_LDS16(g_ + soff[0], &smem[BUF][(REGU16) + (w * 2 + 0) * 512]);      \
    GLOAD_LDS16(g_ + soff[1], &smem[BUF][(REGU16) + (w * 2 + 1) * 512]);      \
} while (0)

#define DSR(D, AD, O) asm volatile("ds_read_b128 %0, %1 offset:" #O          \
                                   : "=v"(D) : "v"(AD))

    // A quadrant reads: offsets qm*8192 + mi*2048 on bases (kk=0: Ak0, kk=1: Ak1)
#define RD_AQ0(F, A0k, A1k) do {                                              \
    DSR(F[0][0], A0k, 0);     DSR(F[0][1], A1k, 0);                           \
    DSR(F[1][0], A0k, 2048);  DSR(F[1][1], A1k, 2048);                        \
    DSR(F[2][0], A0k, 4096);  DSR(F[2][1], A1k, 4096);                        \
    DSR(F[3][0], A0k, 6144);  DSR(F[3][1], A1k, 6144); } while (0)

#define RD_AQ1(F, A0k, A1k) do {                                              \
    DSR(F[0][0], A0k, 8192);  DSR(F[0][1], A1k, 8192);                        \
    DSR(F[1][0], A0k, 10240); DSR(F[1][1], A1k, 10240);                       \
    DSR(F[2][0], A0k, 12288); DSR(F[2][1], A1k, 12288);                       \
    DSR(F[3][0], A0k, 14336); DSR(F[3][1], A1k, 14336); } while (0)

    // B quadrant reads: offsets qn*4096 + nj*2048
#define RD_BQ0(F, B0k, B1k) do {                                              \
    DSR(F[0][0], B0k, 0);     DSR(F[0][1], B1k, 0);                           \
    DSR(F[1][0], B0k, 2048);  DSR(F[1][1], B1k, 2048); } while (0)

#define RD_BQ1(F, B0k, B1k) do {                                              \
    DSR(F[0][0], B0k, 4096);  DSR(F[0][1], B1k, 4096);                        \
    DSR(F[1][0], B0k, 6144);  DSR(F[1][1], B1k, 6144); } while (0)

#define MFMA_Q(QM, QN, AF, BF)                                                \
    _Pragma("unroll") for (int kk = 0; kk < 2; kk++)                          \
    _Pragma("unroll") for (int mi = 0; mi < 4; mi++)                          \
    _Pragma("unroll") for (int nj = 0; nj < 2; nj++)                          \
        acc[(QM) * 4 + mi][(QN) * 2 + nj] = __builtin_amdgcn_mfma_f32_16x16x32_bf16( \
            AF[mi][kk], BF[nj][kk], acc[(QM) * 4 + mi][(QN) * 2 + nj], 0, 0, 0);

#define LGKM0 do { asm volatile("s_waitcnt lgkmcnt(0)" ::: "memory");         \
                   __builtin_amdgcn_sched_barrier(0); } while (0)

    // tile T: read buf CUR (bases A0k..B1k); stream stages per m201.
#define TILE(CUR, NXT, A0k, A1k, B0k, B1k, T) do {                            \
    /* P1: quad(0,0); stage (T+1).A1 -> buf[NXT] */                           \
    STAGE_H(Ab, ((T) + 1) & (NT - 1), 1, NXT, 8192);                          \
    RD_AQ0(afr, A0k, A1k);                                                    \
    RD_BQ0(b0f, B0k, B1k);                                                    \
    __builtin_amdgcn_s_barrier();                                             \
    LGKM0;                                                                    \
    __builtin_amdgcn_s_setprio(1);                                            \
    MFMA_Q(0, 0, afr, b0f);                                                   \
    __builtin_amdgcn_s_setprio(0);                                            \
    __builtin_amdgcn_s_barrier();                                             \
    /* P2: quad(0,1) */                                                       \
    RD_BQ1(b1f, B0k, B1k);                                                    \
    __builtin_amdgcn_s_barrier();                                             \
    LGKM0;                                                                    \
    __builtin_amdgcn_s_setprio(1);                                            \
    MFMA_Q(0, 1, afr, b1f);                                                   \
    __builtin_amdgcn_s_setprio(0);                                            \
    __builtin_amdgcn_s_barrier();                                             \
    /* P3: quad(1,1); stage (T+2).B0 -> buf[CUR] (B free after P2) */         \
    STAGE_H(Bb, ((T) + 2) & (NT - 1), 0, CUR, 16384);                         \
    RD_AQ1(afr, A0k, A1k);                                                    \
    __builtin_amdgcn_s_barrier();                                             \
    LGKM0;                                                                    \
    __builtin_amdgcn_s_setprio(1);                                            \
    MFMA_Q(1, 1, afr, b1f);                                                   \
    __builtin_amdgcn_s_setprio(0);                                            \
    __builtin_amdgcn_s_barrier();                                             \
    /* P4: quad(1,0); stage (T+2).B1 + (T+2).A0 -> buf[CUR] (A free after P3)*/\
    STAGE_H(Bb, ((T) + 2) & (NT - 1), 1, CUR, 24576);                         \
    STAGE_H(Ab, ((T) + 2) & (NT - 1), 0, CUR, 0);                             \
    __builtin_amdgcn_s_setprio(1);                                            \
    MFMA_Q(1, 0, afr, b0f);                                                   \
    __builtin_amdgcn_s_setprio(0);                                            \
    asm volatile("s_waitcnt vmcnt(6)" ::: "memory");                          \
    __builtin_amdgcn_sched_barrier(0);                                        \
    __builtin_amdgcn_s_barrier();                                             \
} while (0)

    bf16x8 afr[4][2], b0f[2][2], b1f[2][2];

    // prologue: t0 all 4 halves (8 loads) + t1.B0,B1,A0 (6 loads);
    // vmcnt(6) certifies t0, leaves t1's 3 halves in flight = steady entry.
    STAGE_H(Ab, 0, 0, 0, 0);
    STAGE_H(Ab, 0, 1, 0, 8192);
    STAGE_H(Bb, 0, 0, 0, 16384);
    STAGE_H(Bb, 0, 1, 0, 24576);
    STAGE_H(Bb, 1, 0, 1, 16384);
    STAGE_H(Bb, 1, 1, 1, 24576);
    STAGE_H(Ab, 1, 0, 1, 0);
    asm volatile("s_waitcnt vmcnt(6)" ::: "memory");
    __builtin_amdgcn_sched_barrier(0);
    __builtin_amdgcn_s_barrier();

    for (int tt = 0; tt < 8; ++tt) {
        const int t0 = 2 * tt, t1 = 2 * tt + 1;
        TILE(0, 1, xA0, xA1, xB0, xB1, t0);
        TILE(1, 0, yA0, yA1, yB0, yB1, t1);
    }

    asm volatile("s_waitcnt vmcnt(0)" ::: "memory");

#undef STAGE_H
#undef DSR
#undef RD_AQ0
#undef RD_AQ1
#undef RD_BQ0
#undef RD_BQ1
#undef MFMA_Q
#undef LGKM0
#undef TILE

    // epilogue: s = sum_nfr v[nfr]*ssp(acc+bias[nfr]); 16-lane shfl reduce;
    // cross-wave (wn) combine in LDS (aliased over smem); store to parts.
    __syncthreads();
    float* red = (float*)&smem[0][0];               // [4][256]
    const bool is_q = (bn >= 2);
    const float* bb2 = is_q ? bc1 : b1;
    const float* vv = is_q ? Wc2 : W2;
    float bias[4], v[4];
#pragma unroll
    for (int nfr = 0; nfr < 4; nfr++) {
        int c = (bn & 1) * 256 + wn * 64 + nfr * 16 + lm;
        bias[nfr] = bb2[c];
        v[nfr] = vv[c];
    }
#pragma unroll
    for (int mfr = 0; mfr < 8; mfr++) {
#pragma unroll
        for (int r = 0; r < 4; r++) {
            float s = 0.0f;
#pragma unroll
            for (int nfr = 0; nfr < 4; nfr++)
                s += v[nfr] * ssp_f(acc[mfr][nfr][r] + bias[nfr]);
            s += __shfl_xor(s, 1);
            s += __shfl_xor(s, 2);
            s += __shfl_xor(s, 4);
            s += __shfl_xor(s, 8);
            if (lm == 0) red[wn * 256 + wm * 128 + mfr * 16 + q * 4 + r] = s;
        }
    }
    __syncthreads();
    if (tid < 256) {
        float val = red[0 * 256 + tid] + red[1 * 256 + tid] +
                    red[2 * 256 + tid] + red[3 * 256 + tid];
        parts[(size_t)bn * 16384 + bm * 256 + tid] = val;
    }
}

// ---------------- coulomb: 256 blocks (8 chunks x 32 batches) ----------------

__global__ __launch_bounds__(256) void coulomb_k(
    const float* __restrict__ R, const float* __restrict__ mask,
    const float* __restrict__ parts, const float* __restrict__ b2p,
    const float* __restrict__ bc2p, float* __restrict__ out)
{
    const int N = 512;
    const int b = blockIdx.y;
    const int chunk = blockIdx.x;
    __shared__ float Rx[512], Ry[512], Rz[512], QM[512];
    __shared__ float rbuf[4];
    const int tid = threadIdx.x;
    const float bc2 = bc2p[0];
    const float b2 = b2p[0];

    for (int j = tid; j < N; j += 256) {
        int idx = b * N + j;
        float m = mask[idx];
        const float* rp = R + (size_t)idx * 3;
        Rx[j] = rp[0];
        Ry[j] = rp[1];
        Rz[j] = rp[2];
        float qv = parts[2 * 16384 + idx] + parts[3 * 16384 + idx] + bc2;
        QM[j] = qv * m;
    }
    __syncthreads();

    const int i = chunk * 64 + (tid & 63);
    const int js = (tid >> 6) * 128;
    const float xi = Rx[i], yi = Ry[i], zi = Rz[i], qmi = QM[i];
    float e = 0.0f;
    for (int j = js; j < js + 128; j++) {
        float dx = xi - Rx[j];
        float dy = yi - Ry[j];
        float dz = zi - Rz[j];
        float d2 = dx * dx + dy * dy + dz * dz;
        float t = 1e-5f + sqrtf(d2);
        float term = qmi * QM[j] / (t * t);
        e += (j == i) ? 0.0f : term;
    }
    if (tid < 64) {
        int ii = b * N + chunk * 64 + tid;
        float yv = parts[0 * 16384 + ii] + parts[1 * 16384 + ii] + b2;
        e += yv * mask[ii];
    }
    for (int off = 32; off > 0; off >>= 1) e += __shfl_down(e, off, 64);
    if ((tid & 63) == 0) rbuf[tid >> 6] = e;
    __syncthreads();
    if (tid == 0) atomicAdd(&out[b], rbuf[0] + rbuf[1] + rbuf[2] + rbuf[3]);
}

// ---------------- fp32 fallback (R1) ----------------

#define BM 128
#define BN 64
#define BK 16

__global__ __launch_bounds__(256) void mlp_gemm(
    const float* __restrict__ A, const float* __restrict__ W1,
    const float* __restrict__ Wc1, const float* __restrict__ b1,
    const float* __restrict__ bc1, const float* __restrict__ W2,
    const float* __restrict__ Wc2, float* __restrict__ yi_part,
    float* __restrict__ q_part)
{
    const int K = 1024;
    const int bm = blockIdx.x;
    const int bn = blockIdx.y;
    const bool is_q = (bn >= 8);
    const float* __restrict__ W = is_q ? Wc1 : W1;
    const int j0 = (bn & 7) * BN;

    __shared__ float As[BK][BM + 4];
    __shared__ float Bs[BK][BN + 4];
    __shared__ float red[BM];

    const int tid = threadIdx.x;
    const int tx = tid & 15;
    const int ty = tid >> 4;

    float acc[8][4];
#pragma unroll
    for (int r = 0; r < 8; r++)
#pragma unroll
        for (int c = 0; c < 4; c++) acc[r][c] = 0.0f;

    const int a_row = tid >> 2;
    const int a_k4 = (tid & 3) * 4;
    const float* Arow0 = A + (size_t)(bm * BM + a_row) * K;
    const float* Arow1 = Arow0 + (size_t)64 * K;
    const int w_k = tid >> 4;
    const int w_j = (tid & 15) * 4;

    for (int kt = 0; kt < K; kt += BK) {
        float4 av0 = *(const float4*)(Arow0 + kt + a_k4);
        float4 av1 = *(const float4*)(Arow1 + kt + a_k4);
        float4 wv = *(const float4*)(W + (size_t)(kt + w_k) * 512 + j0 + w_j);
        __syncthreads();
        As[a_k4 + 0][a_row] = av0.x;
        As[a_k4 + 1][a_row] = av0.y;
        As[a_k4 + 2][a_row] = av0.z;
        As[a_k4 + 3][a_row] = av0.w;
        As[a_k4 + 0][a_row + 64] = av1.x;
        As[a_k4 + 1][a_row + 64] = av1.y;
        As[a_k4 + 2][a_row + 64] = av1.z;
        As[a_k4 + 3][a_row + 64] = av1.w;
        *(float4*)&Bs[w_k][w_j] = wv;
        __syncthreads();
#pragma unroll
        for (int kk = 0; kk < BK; kk++) {
            float4 a0v = *(const float4*)&As[kk][ty * 8];
            float4 a1v = *(const float4*)&As[kk][ty * 8 + 4];
            float4 bv = *(const float4*)&Bs[kk][tx * 4];
            float ar[8] = {a0v.x, a0v.y, a0v.z, a0v.w, a1v.x, a1v.y, a1v.z, a1v.w};
            float bc[4] = {bv.x, bv.y, bv.z, bv.w};
#pragma unroll
            for (int r = 0; r < 8; r++)
#pragma unroll
                for (int c = 0; c < 4; c++)
                    acc[r][c] = fmaf(ar[r], bc[c], acc[r][c]);
        }
    }

    const float* bb = is_q ? bc1 : b1;
    const float* vv = is_q ? Wc2 : W2;
    float bias[4], v[4];
#pragma unroll
    for (int c = 0; c < 4; c++) {
        bias[c] = bb[j0 + tx * 4 + c];
        v[c] = vv[j0 + tx * 4 + c];
    }
    if (tid < BM) red[tid] = 0.0f;
    __syncthreads();
#pragma unroll
    for (int r = 0; r < 8; r++) {
        float s = 0.0f;
#pragma unroll
        for (int c = 0; c < 4; c++)
            s += v[c] * ssp_slow(acc[r][c] + bias[c]);
        atomicAdd(&red[ty * 8 + r], s);
    }
    __syncthreads();
    float* target = is_q ? q_part : yi_part;
    if (tid < BM) atomicAdd(&target[(size_t)bm * BM + tid], red[tid]);
}

__global__ __launch_bounds__(256) void coulomb_fb(
    const float* __restrict__ R, const float* __restrict__ mask,
    const float* __restrict__ yi_part, const float* __restrict__ q_part,
    const float* __restrict__ b2p, const float* __restrict__ bc2p,
    float* __restrict__ out)
{
    const int N = 512;
    const int b = blockIdx.y;
    const int chunk = blockIdx.x;
    __shared__ float Rx[512], Ry[512], Rz[512], QM[512];
    __shared__ float rbuf[4];
    const int tid = threadIdx.x;
    const float bc2 = bc2p[0];
    const float b2 = b2p[0];

    for (int j = tid; j < N; j += 256) {
        float m = mask[b * N + j];
        const float* rp = R + ((size_t)b * N + j) * 3;
        Rx[j] = rp[0];
        Ry[j] = rp[1];
        Rz[j] = rp[2];
        QM[j] = (q_part[b * N + j] + bc2) * m;
    }
    __syncthreads();

    const int i = chunk * 64 + (tid & 63);
    const int js = (tid >> 6) * 128;
    const float xi = Rx[i], yi = Ry[i], zi = Rz[i], qmi = QM[i];
    float e = 0.0f;
    for (int j = js; j < js + 128; j++) {
        float dx = xi - Rx[j];
        float dy = yi - Ry[j];
        float dz = zi - Rz[j];
        float d2 = dx * dx + dy * dy + dz * dz;
        float t = 1e-5f + sqrtf(d2);
        float term = qmi * QM[j] / (t * t);
        e += (j == i) ? 0.0f : term;
    }
    if (tid < 64) {
        int ii = chunk * 64 + tid;
        e += (yi_part[b * N + ii] + b2) * mask[b * N + ii];
    }
    for (int off = 32; off > 0; off >>= 1) e += __shfl_down(e, off, 64);
    if ((tid & 63) == 0) rbuf[tid >> 6] = e;
    __syncthreads();
    if (tid == 0) atomicAdd(&out[b], rbuf[0] + rbuf[1] + rbuf[2] + rbuf[3]);
}

// ---------------- launch ----------------

extern "C" void kernel_launch(void* const* d_in, const int* in_sizes, int n_in,
                              void* d_out, int out_size, void* d_ws, size_t ws_size,
                              hipStream_t stream) {
    const float* rep  = (const float*)d_in[0];
    const float* R    = (const float*)d_in[1];
    const float* mask = (const float*)d_in[2];
    const float* W1   = (const float*)d_in[3];
    const float* b1   = (const float*)d_in[4];
    const float* W2   = (const float*)d_in[5];
    const float* b2   = (const float*)d_in[6];
    const float* Wc1  = (const float*)d_in[7];
    const float* bc1  = (const float*)d_in[8];
    const float* Wc2  = (const float*)d_in[9];
    const float* bc2  = (const float*)d_in[10];
    float* out = (float*)d_out;

    const size_t szA = 16384ull * 1024 * 2;   // 32 MB bf16 A
    const size_t szB = 1024ull * 1024 * 2;    // 2 MB bf16 Bt
    const size_t szP = 8ull * 16384 * 4;      // partials (4 used)
    const size_t need = szA + szB + szP;

    if (ws_size >= need) {
        u16* Abf = (u16*)d_ws;
        u16* Btb = (u16*)((char*)d_ws + szA);
        float* parts = (float*)((char*)d_ws + szA + szB);

        prep<<<8192 + 1024, 256, 0, stream>>>(rep, W1, Wc1, Abf, Btb, out);
        gemm_mfma<<<256, 512, 0, stream>>>(Abf, Btb, b1, W2, bc1, Wc2, parts);
        coulomb_k<<<dim3(8, 32), 256, 0, stream>>>(R, mask, parts, b2, bc2, out);
    } else {
        float* yi_part = (float*)d_ws;
        float* q_part = yi_part + 16384;
        hipMemsetAsync(d_ws, 0, 2 * 16384 * sizeof(float), stream);
        hipMemsetAsync(d_out, 0, 32 * sizeof(float), stream);
        mlp_gemm<<<dim3(128, 16), 256, 0, stream>>>(rep, W1, Wc1, b1, bc1, W2, Wc2,
                                                    yi_part, q_part);
        coulomb_fb<<<dim3(8, 32), 256, 0, stream>>>(R, mask, yi_part, q_part, b2, bc2, out);
    }
}